// Round 1
// baseline (103.785 us; speedup 1.0000x reference)
//
#include <hip/hip_runtime.h>

// Problem constants (reference: B,S,D,H = 2,2048,1024,16)
#define BB 2
#define SS 2048
#define DD 1024

// The attention mask keeps only key index 0 => softmax is exactly one-hot on
// key 0 (exp(-1e9) underflows to 0 in fp32). The whole block reduces to:
//   Vrow[b,f] = sum_d v[b,0,d] * Wv[f,d]
//   yvec[b,e] = sum_f Vrow[b,f] * Wo[e,f]
//   out[b,s,e] = yvec[b,e]   (broadcast over s; q,k,Wq,Wk unused)

// One wave (64 lanes) computes one output row element: y[b,r] = x_b . W[r,:]
__global__ void __launch_bounds__(256)
matvec_rows(const float* __restrict__ W,   // [DD, DD] row-major
            const float* __restrict__ x,   // x + b*xstride = vector of DD floats
            float* __restrict__ y,         // [BB, DD]
            int xstride) {
    const int lane = threadIdx.x & 63;
    const int wave = threadIdx.x >> 6;
    const int gw = blockIdx.x * (blockDim.x >> 6) + wave;  // [0, BB*DD)
    const int b = gw >> 10;    // / DD
    const int r = gw & 1023;   // % DD

    const float* __restrict__ xr = x + b * xstride;
    const float* __restrict__ wr = W + r * DD;

    float acc = 0.f;
    // 1024 = 4 iters * 64 lanes * 4 floats, fully coalesced float4 loads
    #pragma unroll
    for (int i = 0; i < 4; ++i) {
        const int c = (i * 64 + lane) * 4;
        const float4 wv = *(const float4*)(wr + c);
        const float4 xv = *(const float4*)(xr + c);
        acc += wv.x * xv.x + wv.y * xv.y + wv.z * xv.z + wv.w * xv.w;
    }
    // 64-lane butterfly reduce
    #pragma unroll
    for (int off = 32; off > 0; off >>= 1)
        acc += __shfl_down(acc, off, 64);

    if (lane == 0) y[b * DD + r] = acc;
}

// out[b,s,e] = yvec[b,e]; float4-vectorized broadcast write.
__global__ void __launch_bounds__(256)
broadcast_out(const float4* __restrict__ yvec4,  // [BB, DD/4]
              float4* __restrict__ out4) {       // [BB, SS, DD/4]
    const int i = blockIdx.x * blockDim.x + threadIdx.x;  // [0, BB*SS*DD/4)
    const int e4 = i & 255;           // DD/4 = 256
    const int b = i >> 19;            // / (SS * DD/4) = / 524288
    out4[i] = yvec4[(b << 8) + e4];
}

extern "C" void kernel_launch(void* const* d_in, const int* in_sizes, int n_in,
                              void* d_out, int out_size, void* d_ws, size_t ws_size,
                              hipStream_t stream) {
    // inputs: 0=q 1=k 2=v 3=Wq 4=Wk 5=Wv 6=Wo (all float32)
    const float* v  = (const float*)d_in[2];
    const float* Wv = (const float*)d_in[5];
    const float* Wo = (const float*)d_in[6];
    float* out = (float*)d_out;

    float* Vrow = (float*)d_ws;              // [BB, DD]
    float* yvec = Vrow + BB * DD;            // [BB, DD]

    // 1) Vrow[b,f] = v[b,0,:] . Wv[f,:]   (BB*DD waves, 4 waves/block)
    matvec_rows<<<(BB * DD) / 4, 256, 0, stream>>>(Wv, v, Vrow, SS * DD);
    // 2) yvec[b,e] = Vrow[b,:] . Wo[e,:]
    matvec_rows<<<(BB * DD) / 4, 256, 0, stream>>>(Wo, Vrow, yvec, DD);
    // 3) broadcast to all sequence positions
    const int n4 = BB * SS * DD / 4;         // 1,048,576 float4s
    broadcast_out<<<n4 / 256, 256, 0, stream>>>((const float4*)yvec, (float4*)out);
}